// Round 8
// baseline (170.775 us; speedup 1.0000x reference)
//
#include <hip/hip_runtime.h>
#include <math.h>

#define N_NODES 200000
#define NF 128
#define NT 32
#define NS 32
#define NG 128
#define ATILE 64        // nodes per block; 200000 = 3125 * 64 exactly
#define ABLOCKS 3125
#define HPAD 33         // hist/corr stride; slot 32 = dummy overflow bin

typedef short bf16x8 __attribute__((ext_vector_type(8)));
typedef float floatx4 __attribute__((ext_vector_type(4)));

__device__ __forceinline__ float rcp_fast(float x) { return __builtin_amdgcn_rcpf(x); }

// split fp32 into bf16 hi + bf16 lo (RTN both): f ~= hi + lo to ~2^-17 rel
__device__ __forceinline__ void split_bf16(float f, unsigned short& h, unsigned short& l) {
    unsigned u  = __float_as_uint(f);
    unsigned r  = u + 0x7FFFu + ((u >> 16) & 1u);
    unsigned hb = r & 0xFFFF0000u;
    h = (unsigned short)(hb >> 16);
    float rem = f - __uint_as_float(hb);
    unsigned u2 = __float_as_uint(rem);
    unsigned r2 = u2 + 0x7FFFu + ((u2 >> 16) & 1u);
    l = (unsigned short)(r2 >> 16);
}

__device__ __forceinline__ void split8(float4 a, float4 b, bf16x8& h8, bf16x8& l8) {
    unsigned short h[8], l[8];
    split_bf16(a.x, h[0], l[0]); split_bf16(a.y, h[1], l[1]);
    split_bf16(a.z, h[2], l[2]); split_bf16(a.w, h[3], l[3]);
    split_bf16(b.x, h[4], l[4]); split_bf16(b.y, h[5], l[5]);
    split_bf16(b.z, h[6], l[6]); split_bf16(b.w, h[7], l[7]);
    h8 = (bf16x8){(short)h[0],(short)h[1],(short)h[2],(short)h[3],
                  (short)h[4],(short)h[5],(short)h[6],(short)h[7]};
    l8 = (bf16x8){(short)l[0],(short)l[1],(short)l[2],(short)l[3],
                  (short)l[4],(short)l[5],(short)l[6],(short)l[7]};
}

// ---- prep: split v (32x128 fp32) into bf16 hi/lo planes in d_ws ----
__global__ __launch_bounds__(256)
void prep_v(const float* __restrict__ v,
            unsigned short* __restrict__ vh,
            unsigned short* __restrict__ vl)
{
    int j = blockIdx.x * 256 + threadIdx.x;        // 1024 float4s
    if (j >= NT * NF / 4) return;
    float4 val = ((const float4*)v)[j];
    unsigned short h0,h1,h2,h3,l0,l1,l2,l3;
    split_bf16(val.x, h0, l0); split_bf16(val.y, h1, l1);
    split_bf16(val.z, h2, l2); split_bf16(val.w, h3, l3);
    ((ushort4*)vh)[j] = make_ushort4(h0, h1, h2, h3);
    ((ushort4*)vl)[j] = make_ushort4(l0, l1, l2, l3);
}

__global__ __launch_bounds__(256, 6)
void ect_fused(const float* __restrict__ x,
               const int* __restrict__ batch,
               const unsigned short* __restrict__ vh,   // [32][128] bf16, L2-hot
               const unsigned short* __restrict__ vl,
               float* __restrict__ out)
{
    __shared__ unsigned hist[NT * HPAD];   // 4224 B
    __shared__ float    corr[NT * HPAD];   // 4224 B
    __shared__ float    cnt_lds;           // ~8.5 KB total

    const int tid  = threadIdx.x;
    const int blk  = blockIdx.x;
    const int w    = tid >> 6;
    const int lane = tid & 63;
    const int mrow = lane & 15;
    const int quad = lane >> 4;

    // ---- A fragments straight from global: lane owns x row (w*16 + mrow) ----
    const size_t arow = (size_t)blk * ATILE + w * 16 + mrow;
    const float* __restrict__ xrow = x + arow * NF + quad * 8;

    bf16x8 ah[4], al[4];
    #pragma unroll
    for (int slice = 0; slice < 4; ++slice) {
        float4 a0 = *(const float4*)&xrow[slice * 32];
        float4 a1 = *(const float4*)&xrow[slice * 32 + 4];
        split8(a0, a1, ah[slice], al[slice]);
    }

    // ---- B fragments from pre-split global v (no LDS, no barrier) ----
    floatx4 acc0 = {0.f, 0.f, 0.f, 0.f};   // thetas 0..15  (col = mrow)
    floatx4 acc1 = {0.f, 0.f, 0.f, 0.f};   // thetas 16..31
    const int b0off = mrow * NF + quad * 8;
    const int b1off = (16 + mrow) * NF + quad * 8;
    #pragma unroll
    for (int slice = 0; slice < 4; ++slice) {
        bf16x8 bh0 = *(const bf16x8*)&vh[b0off + slice * 32];
        bf16x8 bl0 = *(const bf16x8*)&vl[b0off + slice * 32];
        bf16x8 bh1 = *(const bf16x8*)&vh[b1off + slice * 32];
        bf16x8 bl1 = *(const bf16x8*)&vl[b1off + slice * 32];
        acc0 = __builtin_amdgcn_mfma_f32_16x16x32_bf16(ah[slice], bh0, acc0, 0, 0, 0);
        acc0 = __builtin_amdgcn_mfma_f32_16x16x32_bf16(ah[slice], bl0, acc0, 0, 0, 0);
        acc0 = __builtin_amdgcn_mfma_f32_16x16x32_bf16(al[slice], bh0, acc0, 0, 0, 0);
        acc1 = __builtin_amdgcn_mfma_f32_16x16x32_bf16(ah[slice], bh1, acc1, 0, 0, 0);
        acc1 = __builtin_amdgcn_mfma_f32_16x16x32_bf16(ah[slice], bl1, acc1, 0, 0, 0);
        acc1 = __builtin_amdgcn_mfma_f32_16x16x32_bf16(al[slice], bh1, acc1, 0, 0, 0);
    }
    // C/D layout: col = lane&15 (theta), row = quad*4 + reg (node-in-16-tile)

    // batch labels per-lane from global (256 B region, L2 broadcast)
    const int base = blk * ATILE;
    const int g_first = batch[base];
    const int g_last  = batch[base + ATILE - 1];
    int nlabel[4];
    #pragma unroll
    for (int reg = 0; reg < 4; ++reg)
        nlabel[reg] = batch[base + w * 16 + quad * 4 + reg];

    const float inv_dlin = 14.090909090909092f;  // 31/2.2
    const float Lw       = 10.23848093f;         // SCALE * dlin * log2(e)
    const float dlin     = 2.2f / 31.0f;
    const float L        = 144.26950408889634f;  // SCALE * log2(e)

    const int ft = tid & 31;
    const int sb = tid >> 5;

    for (int gp = g_first; gp <= g_last; ++gp) {   // ~96% of tiles: single pass
        for (int i = tid; i < NT * HPAD; i += 256) { hist[i] = 0u; corr[i] = 0.0f; }
        __syncthreads();

        // sweep directly on the accumulator (C-layout): lane owns 4 nodes x 2 thetas
        #pragma unroll
        for (int reg = 0; reg < 4; ++reg) {
            if (nlabel[reg] == gp) {
                #pragma unroll
                for (int half = 0; half < 2; ++half) {
                    int   t = half ? (16 + mrow) : mrow;
                    float h = half ? acc1[reg] : acc0[reg];
                    float z = fmaf(h, inv_dlin, 15.5f);      // (h + 1.1)/dlin
                    int s_up = (int)ceilf(z);
                    s_up = min(max(s_up, 0), 32);
                    atomicAdd(&hist[t * HPAD + s_up], 1u);
                    int s0 = (int)ceilf(z - 1.45f);
                    #pragma unroll
                    for (int i2 = 0; i2 < 3; ++i2) {
                        int s = s0 + i2;
                        float e   = __builtin_amdgcn_exp2f(Lw * (z - (float)s));
                        float sig = rcp_fast(1.0f + e);
                        float stp = (s >= s_up) ? 1.0f : 0.0f;
                        if (s >= 0 && s <= 31) atomicAdd(&corr[t * HPAD + s], sig - stp);
                    }
                }
            }
        }
        __syncthreads();

        // node count for this graph (wave 0) + prefix-scan hist into corr
        if (tid < ATILE) {
            unsigned long long m = __ballot(batch[base + tid] == gp);
            if (tid == 0) cnt_lds = (float)__popcll(m);
        }
        {
            const int grp = tid >> 5;
            const int s   = tid & 31;
            for (int row = grp; row < NT; row += 8) {
                float val = (float)hist[row * HPAD + s];
                #pragma unroll
                for (int d = 1; d < 32; d <<= 1) {
                    float nbr = __shfl_up(val, d, 32);
                    if (s >= d) val += nbr;
                }
                corr[row * HPAD + s] += val;
            }
        }
        __syncthreads();

        // flush: subtract exact pad term cnt * sigmoid(SCALE*(lin_s - R))
        #pragma unroll
        for (int k = 0; k < 4; ++k) {
            int s = sb + 8 * k;
            float lin_s = -1.1f + (float)s * dlin;
            float cs  = rcp_fast(1.0f + __builtin_amdgcn_exp2f(L * (1.1f - lin_s)));
            float val = corr[ft * HPAD + s] - cnt_lds * cs;
            atomicAdd(&out[(size_t)gp * (NS * NT) + s * NT + ft], val);
        }
        if (gp < g_last) __syncthreads();
    }
}

extern "C" void kernel_launch(void* const* d_in, const int* in_sizes, int n_in,
                              void* d_out, int out_size, void* d_ws, size_t ws_size,
                              hipStream_t stream) {
    const float* x     = (const float*)d_in[0];
    const int*   batch = (const int*)d_in[1];
    const float* v     = (const float*)d_in[3];
    float*       out   = (float*)d_out;

    unsigned short* vh = (unsigned short*)d_ws;          // 32*128 bf16 = 8 KB
    unsigned short* vl = vh + NT * NF;                   // 8 KB

    hipMemsetAsync(d_out, 0, (size_t)out_size * sizeof(float), stream);
    prep_v<<<dim3(4), dim3(256), 0, stream>>>(v, vh, vl);
    ect_fused<<<dim3(ABLOCKS), dim3(256), 0, stream>>>(x, batch, vh, vl, out);
}